// Round 1
// baseline (198470.996 us; speedup 1.0000x reference)
//
#include <hip/hip_runtime.h>
#include <math.h>

#define B_  2048
#define T_  512
#define P_  8
#define L_  64
#define H_  180
#define H3_ 540
#define NR  8
#define NTH 256

struct WPtrs {
  const float* Win; const float* Whp; const float* Wih;
  const float* Whh; const float* Wo1; const float* Wo2;
  int transposed;
};

__device__ __forceinline__ float gelu_f(float v) {
  return 0.5f * v * (1.0f + erff(v * 0.70710678118654752f));
}

struct Smem {
  float phys[NR][P_];    // 64
  float cur [NR][L_];    // 512
  float h   [NR][H_];    // 1440
  float x   [NR][H_];    // 1440
  float gi  [NR][H3_];   // 4320
  float gh  [NR][H3_];   // 4320
  float o1  [NR][H_];    // 1440
  float o2  [NR][L_];    // 512   => 14048 floats = 56,192 B
};

// Generic tiled GEMM: out[r][u] = act( sum_k in[r][k] * W(k,u) + bias[u] )
// W element (k,u) at W[k*wsk + u*wsu].  Items = u*2 + rowgroup; item parity
// == tid parity so each thread owns rows r0..r0+3 only.
template<int MAXIT, int ACT>
__device__ __forceinline__ void gemm_rg8(
    const float* __restrict__ W, int U, int wsk, int wsu,
    const float* inA, int ldA, int KA,
    const float* inB, int ldB, int KB,
    const float* __restrict__ bias,
    float* out, int ldOut)
{
  const int tid = threadIdx.x;
  const int r0  = (tid & 1) * 4;

  int u[MAXIT]; bool val[MAXIT]; int wofs[MAXIT];
#pragma unroll
  for (int m = 0; m < MAXIT; m++) {
    int it = tid + m * NTH;
    val[m] = it < 2 * U;
    int uu = it >> 1; if (uu > U - 1) uu = U - 1;   // clamp: uniform loop body
    u[m] = uu; wofs[m] = uu * wsu;
  }

  float acc[MAXIT][4];
#pragma unroll
  for (int m = 0; m < MAXIT; m++)
#pragma unroll
    for (int rr = 0; rr < 4; rr++) acc[m][rr] = 0.f;

  // ---- part A (k = 0 .. KA-1)
  for (int k4 = 0; k4 < KA; k4 += 4) {
    float inq[4][4];
#pragma unroll
    for (int rr = 0; rr < 4; rr++) {
      float4 t = *(const float4*)&inA[(r0 + rr) * ldA + k4];
      inq[rr][0] = t.x; inq[rr][1] = t.y; inq[rr][2] = t.z; inq[rr][3] = t.w;
    }
#pragma unroll
    for (int dk = 0; dk < 4; dk++) {
      const float* wrow = W + (size_t)(k4 + dk) * wsk;
#pragma unroll
      for (int m = 0; m < MAXIT; m++) {
        float w = wrow[wofs[m]];
#pragma unroll
        for (int rr = 0; rr < 4; rr++)
          acc[m][rr] = fmaf(w, inq[rr][dk], acc[m][rr]);
      }
    }
  }
  // ---- part B (concat rows k = KA .. KA+KB-1)
  for (int k4 = 0; k4 < KB; k4 += 4) {
    float inq[4][4];
#pragma unroll
    for (int rr = 0; rr < 4; rr++) {
      float4 t = *(const float4*)&inB[(r0 + rr) * ldB + k4];
      inq[rr][0] = t.x; inq[rr][1] = t.y; inq[rr][2] = t.z; inq[rr][3] = t.w;
    }
#pragma unroll
    for (int dk = 0; dk < 4; dk++) {
      const float* wrow = W + (size_t)(KA + k4 + dk) * wsk;
#pragma unroll
      for (int m = 0; m < MAXIT; m++) {
        float w = wrow[wofs[m]];
#pragma unroll
        for (int rr = 0; rr < 4; rr++)
          acc[m][rr] = fmaf(w, inq[rr][dk], acc[m][rr]);
      }
    }
  }
  // ---- store
#pragma unroll
  for (int m = 0; m < MAXIT; m++) if (val[m]) {
    float b = bias[u[m]];
#pragma unroll
    for (int rr = 0; rr < 4; rr++) {
      float v = acc[m][rr] + b;
      if (ACT == 1) v = gelu_f(v);
      out[(r0 + rr) * ldOut + u[m]] = v;
    }
  }
}

__global__ __launch_bounds__(NTH)
void rnn_kernel(const float* __restrict__ phys, const float* __restrict__ latents,
                const float* __restrict__ b_in, const float* __restrict__ b_hp,
                const float* __restrict__ b_ih, const float* __restrict__ b_hh,
                const float* __restrict__ b_o1, const float* __restrict__ b_o2,
                WPtrs wp, float* __restrict__ out)
{
  __shared__ Smem s;
  const int tid = threadIdx.x;
  const int b0  = blockIdx.x * NR;
  const int tr  = wp.transposed;

  // init cur = latents
  for (int it = tid; it < NR * L_; it += NTH) {
    int r = it >> 6, l = it & 63;
    s.cur[r][l] = latents[(size_t)(b0 + r) * L_ + l];
  }
  __syncthreads();
  // h0 = latents @ Whp^T + b_hp
  gemm_rg8<2, 0>(wp.Whp, H_, tr ? H_ : 1, tr ? 1 : L_,
                 &s.cur[0][0], L_, L_, nullptr, 0, 0, b_hp, &s.h[0][0], H_);
  __syncthreads();

  for (int t = 0; t < T_; t++) {
    if (tid < NR * P_) {
      int r = tid >> 3, p = tid & 7;
      s.phys[r][p] = phys[((size_t)(b0 + r) * T_ + t) * P_ + p];
    }
    __syncthreads();
    // x = gelu([phys_t, cur] @ Win^T + b_in)
    gemm_rg8<2, 1>(wp.Win, H_, tr ? H_ : 1, tr ? 1 : (P_ + L_),
                   &s.phys[0][0], P_, P_, &s.cur[0][0], L_, L_, b_in, &s.x[0][0], H_);
    __syncthreads();
    // gh = h @ Whh^T + b_hh ; gi = x @ Wih^T + b_ih
    gemm_rg8<5, 0>(wp.Whh, H3_, tr ? H3_ : 1, tr ? 1 : H_,
                   &s.h[0][0], H_, H_, nullptr, 0, 0, b_hh, &s.gh[0][0], H3_);
    gemm_rg8<5, 0>(wp.Wih, H3_, tr ? H3_ : 1, tr ? 1 : H_,
                   &s.x[0][0], H_, H_, nullptr, 0, 0, b_ih, &s.gi[0][0], H3_);
    __syncthreads();
    // GRU gates, h update (in-place; each (r,u) touched by exactly one thread)
    if (tid < H_) {
      for (int r = 0; r < NR; r++) {
        float ir = s.gi[r][tid], iz = s.gi[r][tid + H_], in_ = s.gi[r][tid + 2 * H_];
        float hr = s.gh[r][tid], hz = s.gh[r][tid + H_], hn  = s.gh[r][tid + 2 * H_];
        float rg = 1.f / (1.f + expf(-(ir + hr)));
        float zg = 1.f / (1.f + expf(-(iz + hz)));
        float ng = tanhf(in_ + rg * hn);
        s.h[r][tid] = (1.f - zg) * ng + zg * s.h[r][tid];
      }
    }
    __syncthreads();
    // o1 = gelu([h_new, cur] @ Wo1^T + b_o1)
    gemm_rg8<2, 1>(wp.Wo1, H_, tr ? H_ : 1, tr ? 1 : (H_ + L_),
                   &s.h[0][0], H_, H_, &s.cur[0][0], L_, L_, b_o1, &s.o1[0][0], H_);
    __syncthreads();
    // delta = o1 @ Wo2^T + b_o2
    gemm_rg8<1, 0>(wp.Wo2, L_, tr ? L_ : 1, tr ? 1 : H_,
                   &s.o1[0][0], H_, H_, nullptr, 0, 0, b_o2, &s.o2[0][0], L_);
    __syncthreads();
    // cur = clip(cur + delta, 0, 1); write out[b][t][:]
    for (int it = tid; it < NR * L_; it += NTH) {
      int r = it >> 6, l = it & 63;
      float c = s.cur[r][l] + s.o2[r][l];
      c = fminf(fmaxf(c, 0.f), 1.f);
      s.cur[r][l] = c;
      out[((size_t)(b0 + r) * T_ + t) * L_ + l] = c;
    }
    __syncthreads();
  }
}

// Transpose all weights [U][K] -> [K][U] into ws.
__global__ void prep_kernel(const float* W0, const float* W1, const float* W2,
                            const float* W3, const float* W4, const float* W5,
                            float* ws)
{
  int gid = blockIdx.x * blockDim.x + threadIdx.x;
  const int Ks[6] = {72, 64, 180, 180, 244, 180};
  const int Us[6] = {180, 180, 540, 540, 180, 64};
  const float* Wsrc[6] = {W0, W1, W2, W3, W4, W5};
  int base = 0;
#pragma unroll
  for (int i = 0; i < 6; i++) {
    int n = Ks[i] * Us[i];
    if (gid >= base && gid < base + n) {
      int e = gid - base;
      int k = e / Us[i], u = e - k * Us[i];
      ws[gid] = Wsrc[i][u * Ks[i] + k];
    }
    base += n;
  }
}

extern "C" void kernel_launch(void* const* d_in, const int* in_sizes, int n_in,
                              void* d_out, int out_size, void* d_ws, size_t ws_size,
                              hipStream_t stream)
{
  const float* phys    = (const float*)d_in[0];
  const float* latents = (const float*)d_in[1];
  const float* W_in = (const float*)d_in[2];  const float* b_in = (const float*)d_in[3];
  const float* W_hp = (const float*)d_in[4];  const float* b_hp = (const float*)d_in[5];
  const float* W_ih = (const float*)d_in[6];  const float* b_ih = (const float*)d_in[7];
  const float* W_hh = (const float*)d_in[8];  const float* b_hh = (const float*)d_in[9];
  const float* W_o1 = (const float*)d_in[10]; const float* b_o1 = (const float*)d_in[11];
  const float* W_o2 = (const float*)d_in[12]; const float* b_o2 = (const float*)d_in[13];

  float* ws = (float*)d_ws;
  const size_t need = 274320u * sizeof(float);
  WPtrs wp;
  if (ws_size >= need) {
    prep_kernel<<<(274320 + 255) / 256, 256, 0, stream>>>(W_in, W_hp, W_ih, W_hh, W_o1, W_o2, ws);
    wp.Win = ws;           wp.Whp = ws + 12960;  wp.Wih = ws + 24480;
    wp.Whh = ws + 121680;  wp.Wo1 = ws + 218880; wp.Wo2 = ws + 262800;
    wp.transposed = 1;
  } else {
    wp.Win = W_in; wp.Whp = W_hp; wp.Wih = W_ih;
    wp.Whh = W_hh; wp.Wo1 = W_o1; wp.Wo2 = W_o2;
    wp.transposed = 0;
  }
  rnn_kernel<<<B_ / NR, NTH, 0, stream>>>(phys, latents, b_in, b_hp, b_ih, b_hh,
                                          b_o1, b_o2, wp, (float*)d_out);
}

// Round 2
// 7082.091 us; speedup vs baseline: 28.0244x; 28.0244x over previous
//
#include <hip/hip_runtime.h>
#include <hip/hip_bf16.h>
#include <math.h>

#define B_  2048
#define T_  512
#define P_  8
#define L_  64
#define H_  180
#define H3_ 540

// ---------------- common helpers ----------------
__device__ __forceinline__ float gelu_f(float v) {
  return 0.5f * v * (1.0f + erff(v * 0.70710678118654752f));
}

// =====================================================================
//  MFMA path: 128 blocks x 16 rows, 512 threads (8 waves)
// =====================================================================
typedef __attribute__((ext_vector_type(8))) short bf16x8;
typedef __attribute__((ext_vector_type(4))) float f32x4;

#define NROW 16
#define NTHM 512

// LDS layout (bytes, all 16-aligned)
// gi   fp32 [16][548]   @ 0        (35072)
// gh   fp32 [16][548]   @ 35072    (35072)
// h32  fp32 [16][180]   @ 70144    (11520)
// cur32 fp32[16][68]    @ 81664    (4352)
// xin  bf16 [16][104]   @ 86016    (3328)
// latb bf16 [16][72]    @ 89344    (2304)
// xb   bf16 [16][200]   @ 91648    (6400)
// hb   bf16 [16][200]   @ 98048    (6400)
// o1in bf16 [16][264]   @ 104448   (8448)
// o1b  bf16 [16][200]   @ 112896   (6400)
#define SMEM_BYTES 119296

struct Streams {
  const char *win, *whp, *wih, *whh, *wo1, *wo2;
};

__device__ __forceinline__ short tobf(float f) {
  __hip_bfloat16 h = __float2bfloat16(f);
  short s; __builtin_memcpy(&s, &h, 2); return s;
}

template<int KC> struct AF { bf16x8 a[KC]; };

template<int KC>
__device__ __forceinline__ AF<KC> load_af(const short* base, int strideShorts, int lane) {
  AF<KC> r;
  const char* p = (const char*)(base + (size_t)(lane & 15) * strideShorts) + ((lane >> 4) * 16);
#pragma unroll
  for (int c = 0; c < KC; c++) r.a[c] = *(const bf16x8*)(p + c * 64);
  return r;
}

// One 16-wide output tile column: stream KC K-chunks of (hi,lo) B-fragments.
template<int KC>
__device__ __forceinline__ f32x4 wcol(const char* __restrict__ wtile, int lane,
                                      const AF<KC>& af, f32x4 acc) {
  bf16x8 b[2 * KC];
#pragma unroll
  for (int c = 0; c < KC; c++) {
    b[2*c]     = *(const bf16x8*)(wtile + c * 2048 + lane * 16);
    b[2*c + 1] = *(const bf16x8*)(wtile + c * 2048 + 1024 + lane * 16);
  }
#pragma unroll
  for (int c = 0; c < KC; c++) {
    acc = __builtin_amdgcn_mfma_f32_16x16x32_bf16(af.a[c], b[2*c], acc, 0, 0, 0);
    acc = __builtin_amdgcn_mfma_f32_16x16x32_bf16(af.a[c], b[2*c + 1], acc, 0, 0, 0);
  }
  return acc;
}

__device__ __forceinline__ f32x4 bias4(const float* __restrict__ b, int n, int lane, int U) {
  int u = n * 16 + (lane & 15);
  float v = (u < U) ? b[u] : 0.f;
  f32x4 r = {v, v, v, v};
  return r;
}

__global__ __launch_bounds__(NTHM)
void rnn_mfma(const float* __restrict__ phys, const float* __restrict__ latents,
              const float* __restrict__ b_in, const float* __restrict__ b_hp,
              const float* __restrict__ b_ih, const float* __restrict__ b_hh,
              const float* __restrict__ b_o1, const float* __restrict__ b_o2,
              Streams st, float* __restrict__ out)
{
  extern __shared__ char smem_raw[];
  float* gi    = (float*)(smem_raw);
  float* gh    = (float*)(smem_raw + 35072);
  float* h32   = (float*)(smem_raw + 70144);
  float* cur32 = (float*)(smem_raw + 81664);
  short* xin   = (short*)(smem_raw + 86016);
  short* latb  = (short*)(smem_raw + 89344);
  short* xb    = (short*)(smem_raw + 91648);
  short* hb    = (short*)(smem_raw + 98048);
  short* o1in  = (short*)(smem_raw + 104448);
  short* o1b   = (short*)(smem_raw + 112896);

  const int tid  = threadIdx.x;
  const int lane = tid & 63;
  const int wv   = tid >> 6;
  const int b0   = blockIdx.x * NROW;

  // ---- init: zero pads, stage latents (cur32 + latb) ----
  for (int it = tid; it < 16 * 24; it += NTHM) {          // xin k-pad [72,96)
    int r = it / 24, c = it - r * 24;
    xin[r * 104 + 72 + c] = 0;
  }
  for (int it = tid; it < 16 * 12; it += NTHM) {          // o1in k-pad [244,256)
    int r = it / 12, c = it - r * 12;
    o1in[r * 264 + 244 + c] = 0;
  }
  for (int it = tid; it < 16 * 64; it += NTHM) {
    int r = it >> 6, l = it & 63;
    float c = latents[(size_t)(b0 + r) * L_ + l];
    cur32[r * 68 + l] = c;
    latb[r * 72 + l]  = tobf(c);
  }
  __syncthreads();

  // ---- h0 = latents @ Whp^T + b_hp (no activation) ----
  {
    AF<2> af = load_af<2>(latb, 72, lane);
    for (int n = wv; n < 12; n += 8) {
      f32x4 acc = bias4(b_hp, n, lane, H_);
      acc = wcol<2>(st.whp + (size_t)n * 2 * 2048, lane, af, acc);
      int u = n * 16 + (lane & 15), rb = (lane >> 4) * 4;
#pragma unroll
      for (int g = 0; g < 4; g++) {
        if (u < H_) h32[(rb + g) * 180 + u] = acc[g];
        hb[(rb + g) * 200 + u] = tobf(acc[g]);   // pads (u>=180) get bf16(0)
      }
    }
  }
  __syncthreads();

#pragma unroll 1
  for (int t = 0; t < T_; t++) {
    // ---- pass1: stage phys_t + cur (bf16) ----
    if (tid < 128) {
      int r = tid >> 3, p = tid & 7;
      xin[r * 104 + p] = tobf(phys[((size_t)(b0 + r) * T_ + t) * P_ + p]);
    }
    for (int it = tid; it < 1024; it += NTHM) {
      int r = it >> 6, l = it & 63;
      short cb = tobf(cur32[r * 68 + l]);
      xin[r * 104 + 8 + l]    = cb;
      o1in[r * 264 + 180 + l] = cb;
    }
    __syncthreads();

    // ---- GEMM1: x = gelu([phys|cur] @ Win^T + b_in) -> xb ----
    {
      AF<3> af = load_af<3>(xin, 104, lane);
      for (int n = wv; n < 12; n += 8) {
        f32x4 acc = bias4(b_in, n, lane, H_);
        acc = wcol<3>(st.win + (size_t)n * 3 * 2048, lane, af, acc);
        int u = n * 16 + (lane & 15), rb = (lane >> 4) * 4;
#pragma unroll
        for (int g = 0; g < 4; g++) xb[(rb + g) * 200 + u] = tobf(gelu_f(acc[g]));
      }
    }
    __syncthreads();

    // ---- GEMM2: gi = x@Wih^T + b_ih ; gh = h@Whh^T + b_hh ----
    {
      AF<6> ax = load_af<6>(xb, 200, lane);
      AF<6> ah = load_af<6>(hb, 200, lane);
      for (int tt = wv; tt < 68; tt += 8) {
        bool isg = tt < 34;
        int n = isg ? tt : tt - 34;
        const char* w = (isg ? st.wih : st.whh) + (size_t)n * 6 * 2048;
        f32x4 acc = bias4(isg ? b_ih : b_hh, n, lane, H3_);
        acc = isg ? wcol<6>(w, lane, ax, acc) : wcol<6>(w, lane, ah, acc);
        float* o = isg ? gi : gh;
        int u = n * 16 + (lane & 15), rb = (lane >> 4) * 4;
#pragma unroll
        for (int g = 0; g < 4; g++) o[(rb + g) * 548 + u] = acc[g];
      }
    }
    __syncthreads();

    // ---- gates (fp32 state update) ----
    for (int it = tid; it < 16 * H_; it += NTHM) {
      int r = it & 15, u = it >> 4;
      float ir = gi[r * 548 + u], iz = gi[r * 548 + u + 180], in_ = gi[r * 548 + u + 360];
      float hr = gh[r * 548 + u], hz = gh[r * 548 + u + 180], hn  = gh[r * 548 + u + 360];
      float rg = 1.f / (1.f + expf(-(ir + hr)));
      float zg = 1.f / (1.f + expf(-(iz + hz)));
      float ng = tanhf(in_ + rg * hn);
      float hN = (1.f - zg) * ng + zg * h32[r * 180 + u];
      h32[r * 180 + u] = hN;
      short hbv = tobf(hN);
      hb[r * 200 + u]   = hbv;
      o1in[r * 264 + u] = hbv;
    }
    __syncthreads();

    // ---- GEMM3: o1 = gelu([h|cur] @ Wo1^T + b_o1) -> o1b ----
    {
      AF<8> af = load_af<8>(o1in, 264, lane);
      for (int n = wv; n < 12; n += 8) {
        f32x4 acc = bias4(b_o1, n, lane, H_);
        acc = wcol<8>(st.wo1 + (size_t)n * 8 * 2048, lane, af, acc);
        int u = n * 16 + (lane & 15), rb = (lane >> 4) * 4;
#pragma unroll
        for (int g = 0; g < 4; g++) o1b[(rb + g) * 200 + u] = tobf(gelu_f(acc[g]));
      }
    }
    __syncthreads();

    // ---- GEMM4: delta = o1 @ Wo2^T + b_o2; cur = clip(cur+delta) ----
    {
      AF<6> af = load_af<6>(o1b, 200, lane);
      for (int n = wv; n < 4; n += 8) {
        f32x4 acc = bias4(b_o2, n, lane, L_);
        acc = wcol<6>(st.wo2 + (size_t)n * 6 * 2048, lane, af, acc);
        int l = n * 16 + (lane & 15), rb = (lane >> 4) * 4;
#pragma unroll
        for (int g = 0; g < 4; g++) {
          int idx = (rb + g) * 68 + l;
          float v = cur32[idx] + acc[g];
          v = fminf(fmaxf(v, 0.f), 1.f);
          cur32[idx] = v;
        }
      }
    }
    __syncthreads();

    // ---- coalesced out write (256B per row) ----
    if (tid < 256) {
      int r = tid >> 4, q = tid & 15;
      float4 v;
      v.x = cur32[r * 68 + q * 4 + 0];
      v.y = cur32[r * 68 + q * 4 + 1];
      v.z = cur32[r * 68 + q * 4 + 2];
      v.w = cur32[r * 68 + q * 4 + 3];
      *(float4*)&out[((size_t)(b0 + r) * T_ + t) * L_ + q * 4] = v;
    }
    // no barrier needed: next writer of cur32 is GEMM4(t+1), 5 barriers away
  }
}

// ---- prep: pack W into hi/lo bf16 B-fragment streams ----
// stream layout per GEMM: [n][c][hl][lane][8 bf16] ; 16 B per (line)
// sections in order: Win, Whp, Wih, Whh, Wo1, Wo2 ; 75264 lines total
__global__ void prep_mfma(const float* __restrict__ W_in, const float* __restrict__ W_hp,
                          const float* __restrict__ W_ih, const float* __restrict__ W_hh,
                          const float* __restrict__ W_o1, const float* __restrict__ W_o2,
                          char* __restrict__ ws)
{
  int gid = blockIdx.x * blockDim.x + threadIdx.x;
  if (gid >= 75264) return;
  const float* Ws[6] = {W_in, W_hp, W_ih, W_hh, W_o1, W_o2};
  const int Us[6]  = {180, 180, 540, 540, 180, 64};
  const int Ks[6]  = {72, 64, 180, 180, 244, 180};
  const int Kcs[6] = {3, 2, 6, 6, 8, 6};
  const int NT[6]  = {12, 12, 34, 34, 12, 4};
  int s = 0, base = 0;
  for (s = 0; s < 6; s++) {
    int lines = NT[s] * Kcs[s] * 128;
    if (gid < base + lines) break;
    base += lines;
  }
  int line = gid - base;
  int nc = line >> 7, r = line & 127;
  int hl = r >> 6, ln = r & 63;
  int n = nc / Kcs[s], c = nc - n * Kcs[s];
  int u  = n * 16 + (ln & 15);
  int k0 = c * 32 + (ln >> 4) * 8;
  union { short sh[8]; int4 v; } pk;
#pragma unroll
  for (int j = 0; j < 8; j++) {
    int k = k0 + j;
    float w = (u < Us[s] && k < Ks[s]) ? Ws[s][(size_t)u * Ks[s] + k] : 0.f;
    __hip_bfloat16 hi = __float2bfloat16(w);
    float hif = __bfloat162float(hi);
    __hip_bfloat16 lo = __float2bfloat16(w - hif);
    __hip_bfloat16 o = hl ? lo : hi;
    short sv; __builtin_memcpy(&sv, &o, 2);
    pk.sh[j] = sv;
  }
  *(int4*)(ws + (size_t)gid * 16) = pk.v;
}

// =====================================================================
//  Fallback path (round-1, proven correct) — used only if ws too small
// =====================================================================
#define NR  8
#define NTH 256
struct WPtrs {
  const float* Win; const float* Whp; const float* Wih;
  const float* Whh; const float* Wo1; const float* Wo2;
  int transposed;
};
struct Smem {
  float phys[NR][P_]; float cur[NR][L_]; float h[NR][H_]; float x[NR][H_];
  float gi[NR][H3_]; float gh[NR][H3_]; float o1[NR][H_]; float o2[NR][L_];
};
template<int MAXIT, int ACT>
__device__ __forceinline__ void gemm_rg8(
    const float* __restrict__ W, int U, int wsk, int wsu,
    const float* inA, int ldA, int KA,
    const float* inB, int ldB, int KB,
    const float* __restrict__ bias, float* out, int ldOut)
{
  const int tid = threadIdx.x;
  const int r0  = (tid & 1) * 4;
  int u[MAXIT]; bool val[MAXIT]; int wofs[MAXIT];
#pragma unroll
  for (int m = 0; m < MAXIT; m++) {
    int it = tid + m * NTH;
    val[m] = it < 2 * U;
    int uu = it >> 1; if (uu > U - 1) uu = U - 1;
    u[m] = uu; wofs[m] = uu * wsu;
  }
  float acc[MAXIT][4];
#pragma unroll
  for (int m = 0; m < MAXIT; m++)
#pragma unroll
    for (int rr = 0; rr < 4; rr++) acc[m][rr] = 0.f;
  for (int k4 = 0; k4 < KA; k4 += 4) {
    float inq[4][4];
#pragma unroll
    for (int rr = 0; rr < 4; rr++) {
      float4 tq = *(const float4*)&inA[(r0 + rr) * ldA + k4];
      inq[rr][0] = tq.x; inq[rr][1] = tq.y; inq[rr][2] = tq.z; inq[rr][3] = tq.w;
    }
#pragma unroll
    for (int dk = 0; dk < 4; dk++) {
      const float* wrow = W + (size_t)(k4 + dk) * wsk;
#pragma unroll
      for (int m = 0; m < MAXIT; m++) {
        float w = wrow[wofs[m]];
#pragma unroll
        for (int rr = 0; rr < 4; rr++) acc[m][rr] = fmaf(w, inq[rr][dk], acc[m][rr]);
      }
    }
  }
  for (int k4 = 0; k4 < KB; k4 += 4) {
    float inq[4][4];
#pragma unroll
    for (int rr = 0; rr < 4; rr++) {
      float4 tq = *(const float4*)&inB[(r0 + rr) * ldB + k4];
      inq[rr][0] = tq.x; inq[rr][1] = tq.y; inq[rr][2] = tq.z; inq[rr][3] = tq.w;
    }
#pragma unroll
    for (int dk = 0; dk < 4; dk++) {
      const float* wrow = W + (size_t)(KA + k4 + dk) * wsk;
#pragma unroll
      for (int m = 0; m < MAXIT; m++) {
        float w = wrow[wofs[m]];
#pragma unroll
        for (int rr = 0; rr < 4; rr++) acc[m][rr] = fmaf(w, inq[rr][dk], acc[m][rr]);
      }
    }
  }
#pragma unroll
  for (int m = 0; m < MAXIT; m++) if (val[m]) {
    float b = bias[u[m]];
#pragma unroll
    for (int rr = 0; rr < 4; rr++) {
      float v = acc[m][rr] + b;
      if (ACT == 1) v = gelu_f(v);
      out[(r0 + rr) * ldOut + u[m]] = v;
    }
  }
}
__global__ __launch_bounds__(NTH)
void rnn_kernel(const float* __restrict__ phys, const float* __restrict__ latents,
                const float* __restrict__ b_in, const float* __restrict__ b_hp,
                const float* __restrict__ b_ih, const float* __restrict__ b_hh,
                const float* __restrict__ b_o1, const float* __restrict__ b_o2,
                WPtrs wp, float* __restrict__ out)
{
  __shared__ Smem s;
  const int tid = threadIdx.x;
  const int b0  = blockIdx.x * NR;
  const int tr  = wp.transposed;
  for (int it = tid; it < NR * L_; it += NTH) {
    int r = it >> 6, l = it & 63;
    s.cur[r][l] = latents[(size_t)(b0 + r) * L_ + l];
  }
  __syncthreads();
  gemm_rg8<2, 0>(wp.Whp, H_, tr ? H_ : 1, tr ? 1 : L_,
                 &s.cur[0][0], L_, L_, nullptr, 0, 0, b_hp, &s.h[0][0], H_);
  __syncthreads();
  for (int t = 0; t < T_; t++) {
    if (tid < NR * P_) {
      int r = tid >> 3, p = tid & 7;
      s.phys[r][p] = phys[((size_t)(b0 + r) * T_ + t) * P_ + p];
    }
    __syncthreads();
    gemm_rg8<2, 1>(wp.Win, H_, tr ? H_ : 1, tr ? 1 : (P_ + L_),
                   &s.phys[0][0], P_, P_, &s.cur[0][0], L_, L_, b_in, &s.x[0][0], H_);
    __syncthreads();
    gemm_rg8<5, 0>(wp.Whh, H3_, tr ? H3_ : 1, tr ? 1 : H_,
                   &s.h[0][0], H_, H_, nullptr, 0, 0, b_hh, &s.gh[0][0], H3_);
    gemm_rg8<5, 0>(wp.Wih, H3_, tr ? H3_ : 1, tr ? 1 : H_,
                   &s.x[0][0], H_, H_, nullptr, 0, 0, b_ih, &s.gi[0][0], H3_);
    __syncthreads();
    if (tid < H_) {
      for (int r = 0; r < NR; r++) {
        float ir = s.gi[r][tid], iz = s.gi[r][tid + H_], in_ = s.gi[r][tid + 2 * H_];
        float hr = s.gh[r][tid], hz = s.gh[r][tid + H_], hn  = s.gh[r][tid + 2 * H_];
        float rg = 1.f / (1.f + expf(-(ir + hr)));
        float zg = 1.f / (1.f + expf(-(iz + hz)));
        float ng = tanhf(in_ + rg * hn);
        s.h[r][tid] = (1.f - zg) * ng + zg * s.h[r][tid];
      }
    }
    __syncthreads();
    gemm_rg8<2, 1>(wp.Wo1, H_, tr ? H_ : 1, tr ? 1 : (H_ + L_),
                   &s.h[0][0], H_, H_, &s.cur[0][0], L_, L_, b_o1, &s.o1[0][0], H_);
    __syncthreads();
    gemm_rg8<1, 0>(wp.Wo2, L_, tr ? L_ : 1, tr ? 1 : H_,
                   &s.o1[0][0], H_, H_, nullptr, 0, 0, b_o2, &s.o2[0][0], L_);
    __syncthreads();
    for (int it = tid; it < NR * L_; it += NTH) {
      int r = it >> 6, l = it & 63;
      float c = s.cur[r][l] + s.o2[r][l];
      c = fminf(fmaxf(c, 0.f), 1.f);
      s.cur[r][l] = c;
      out[((size_t)(b0 + r) * T_ + t) * L_ + l] = c;
    }
    __syncthreads();
  }
}
__global__ void prep_kernel(const float* W0, const float* W1, const float* W2,
                            const float* W3, const float* W4, const float* W5,
                            float* ws)
{
  int gid = blockIdx.x * blockDim.x + threadIdx.x;
  const int Ksx[6] = {72, 64, 180, 180, 244, 180};
  const int Usx[6] = {180, 180, 540, 540, 180, 64};
  const float* Wsrc[6] = {W0, W1, W2, W3, W4, W5};
  int base = 0;
#pragma unroll
  for (int i = 0; i < 6; i++) {
    int n = Ksx[i] * Usx[i];
    if (gid >= base && gid < base + n) {
      int e = gid - base;
      int k = e / Usx[i], u = e - k * Usx[i];
      ws[gid] = Wsrc[i][u * Ksx[i] + k];
    }
    base += n;
  }
}

// =====================================================================
extern "C" void kernel_launch(void* const* d_in, const int* in_sizes, int n_in,
                              void* d_out, int out_size, void* d_ws, size_t ws_size,
                              hipStream_t stream)
{
  const float* phys    = (const float*)d_in[0];
  const float* latents = (const float*)d_in[1];
  const float* W_in = (const float*)d_in[2];  const float* b_in = (const float*)d_in[3];
  const float* W_hp = (const float*)d_in[4];  const float* b_hp = (const float*)d_in[5];
  const float* W_ih = (const float*)d_in[6];  const float* b_ih = (const float*)d_in[7];
  const float* W_hh = (const float*)d_in[8];  const float* b_hh = (const float*)d_in[9];
  const float* W_o1 = (const float*)d_in[10]; const float* b_o1 = (const float*)d_in[11];
  const float* W_o2 = (const float*)d_in[12]; const float* b_o2 = (const float*)d_in[13];

  const size_t need_mfma = 75264u * 16u;   // 1,204,224 B
  if (ws_size >= need_mfma) {
    char* ws = (char*)d_ws;
    prep_mfma<<<(75264 + 255) / 256, 256, 0, stream>>>(W_in, W_hp, W_ih, W_hh, W_o1, W_o2, ws);
    Streams st;
    st.win = ws;
    st.whp = ws + (size_t)4608 * 16;
    st.wih = ws + (size_t)(4608 + 3072) * 16;
    st.whh = ws + (size_t)(4608 + 3072 + 26112) * 16;
    st.wo1 = ws + (size_t)(4608 + 3072 + 26112 + 26112) * 16;
    st.wo2 = ws + (size_t)(4608 + 3072 + 26112 + 26112 + 12288) * 16;
    (void)hipFuncSetAttribute((const void*)rnn_mfma,
                              hipFuncAttributeMaxDynamicSharedMemorySize, SMEM_BYTES);
    rnn_mfma<<<B_ / NROW, NTHM, SMEM_BYTES, stream>>>(
        phys, latents, b_in, b_hp, b_ih, b_hh, b_o1, b_o2, st, (float*)d_out);
  } else {
    // round-1 fallback
    float* ws = (float*)d_ws;
    const size_t need = 274320u * sizeof(float);
    WPtrs wp;
    if (ws_size >= need) {
      prep_kernel<<<(274320 + 255) / 256, 256, 0, stream>>>(W_in, W_hp, W_ih, W_hh, W_o1, W_o2, ws);
      wp.Win = ws;           wp.Whp = ws + 12960;  wp.Wih = ws + 24480;
      wp.Whh = ws + 121680;  wp.Wo1 = ws + 218880; wp.Wo2 = ws + 262800;
      wp.transposed = 1;
    } else {
      wp.Win = W_in; wp.Whp = W_hp; wp.Wih = W_ih;
      wp.Whh = W_hh; wp.Wo1 = W_o1; wp.Wo2 = W_o2;
      wp.transposed = 0;
    }
    rnn_kernel<<<B_ / NR, NTH, 0, stream>>>(phys, latents, b_in, b_hp, b_ih, b_hh,
                                            b_o1, b_o2, wp, (float*)d_out);
  }
}